// Round 6
// baseline (555.725 us; speedup 1.0000x reference)
//
#include <hip/hip_runtime.h>
#include <hip/hip_bf16.h>
#include <math.h>

#define NTOK 8192
#define DM 512
#define DFF 2048
#define NE 8
#define ROWCAP 33792   // 32768 assignments max + 8*128 granule padding

typedef __attribute__((ext_vector_type(8))) short bfrag;
typedef __attribute__((ext_vector_type(4))) float f32x4;
typedef __attribute__((ext_vector_type(4))) unsigned int u32x4;
typedef __attribute__((ext_vector_type(4))) short s16x4;

// async global->LDS, 16B/lane; LDS dest = wave-uniform base + lane*16 (global addr may be per-lane)
#define GLD_LDS16(gp, lp) __builtin_amdgcn_global_load_lds( \
    (const __attribute__((address_space(1))) void*)(gp),    \
    (__attribute__((address_space(3))) void*)(lp), 16, 0, 0)

__device__ __forceinline__ short f2bf(float f) {
  unsigned u = __builtin_bit_cast(unsigned, f);
  u += 0x7fffu + ((u >> 16) & 1u);
  return (short)(u >> 16);
}
__device__ __forceinline__ float bf2f(short s) {
  unsigned u = ((unsigned)(unsigned short)s) << 16;
  return __builtin_bit_cast(float, u);
}
// tanh-form GELU via hw exp2+rcp (~7 ops). max |diff vs erf-gelu| ~5e-4.
__device__ __forceinline__ float fast_gelu(float v) {
  float u = fmaf(v * v * v, 0.044715f, v) * 0.7978845608f;
  float ex = __builtin_amdgcn_exp2f(u * -2.8853900818f);
  return v * __builtin_amdgcn_rcpf(1.f + ex);
}

// ---------------- fp32 -> bf16 conversion ----------------
__global__ __launch_bounds__(256) void cvt_kernel(const float* __restrict__ in,
                                                  short* __restrict__ o, int n4) {
  int i = blockIdx.x * 256 + threadIdx.x;
  if (i >= n4) return;
  f32x4 v = ((const f32x4*)in)[i];
  s16x4 s;
  #pragma unroll
  for (int j = 0; j < 4; j++) s[j] = f2bf(v[j]);
  ((s16x4*)o)[i] = s;
}

// ---------------- fp32 -> bf16 transpose-convert ----------------
__global__ __launch_bounds__(256) void cvtT_kernel(const float* __restrict__ in,
                                                   short* __restrict__ o, int R, int C) {
  __shared__ float t[32][33];
  size_t eoff = (size_t)blockIdx.z * R * C;
  in += eoff; o += eoff;
  int r0 = blockIdx.x * 32, c0 = blockIdx.y * 32;
  int tx = threadIdx.x & 31, ty = threadIdx.x >> 5;
  #pragma unroll
  for (int i = 0; i < 32; i += 8)
    t[ty + i][tx] = in[(size_t)(r0 + ty + i) * C + c0 + tx];
  __syncthreads();
  #pragma unroll
  for (int i = 0; i < 32; i += 8)
    o[(size_t)(c0 + ty + i) * R + r0 + tx] = f2bf(t[tx][ty + i]);
}

// ---------------- router ----------------
__global__ __launch_bounds__(256) void router_kernel(const float* __restrict__ x,
                                                     const float* __restrict__ rw,
                                                     int* __restrict__ sel_e,
                                                     float* __restrict__ sel_w,
                                                     float* __restrict__ part) {
  __shared__ float s_cnt[NE], s_ps[NE];
  int tid = threadIdx.x;
  if (tid < NE) { s_cnt[tid] = 0.f; s_ps[tid] = 0.f; }
  __syncthreads();
  int wave = tid >> 6, lane = tid & 63;
  float myc[NE], myp[NE];
  #pragma unroll
  for (int e = 0; e < NE; e++) { myc[e] = 0.f; myp[e] = 0.f; }

  for (int i = 0; i < 8; i++) {
    int token = blockIdx.x * 32 + wave * 8 + i;
    const float* xt = x + (size_t)token * DM;
    float acc[NE];
    #pragma unroll
    for (int e = 0; e < NE; e++) acc[e] = 0.f;
    #pragma unroll
    for (int kk = 0; kk < DM / 64; kk++) {
      int k = kk * 64 + lane;
      float xv = xt[k];
      f32x4 r0 = *(const f32x4*)(rw + k * NE);
      f32x4 r1 = *(const f32x4*)(rw + k * NE + 4);
      acc[0] += xv * r0[0]; acc[1] += xv * r0[1]; acc[2] += xv * r0[2]; acc[3] += xv * r0[3];
      acc[4] += xv * r1[0]; acc[5] += xv * r1[1]; acc[6] += xv * r1[2]; acc[7] += xv * r1[3];
    }
    #pragma unroll
    for (int off = 32; off >= 1; off >>= 1) {
      #pragma unroll
      for (int e = 0; e < NE; e++) acc[e] += __shfl_xor(acc[e], off, 64);
    }
    float mx = acc[0];
    #pragma unroll
    for (int e = 1; e < NE; e++) mx = fmaxf(mx, acc[e]);
    float p[NE]; float sum = 0.f;
    #pragma unroll
    for (int e = 0; e < NE; e++) { p[e] = expf(acc[e] - mx); sum += p[e]; }
    float inv = 1.f / sum;
    #pragma unroll
    for (int e = 0; e < NE; e++) p[e] *= inv;
    float sp[4]; int si[4]; unsigned used = 0;
    #pragma unroll
    for (int s = 0; s < 4; s++) {
      float bp = -1.f; int bi = 0;
      #pragma unroll
      for (int e = 0; e < NE; e++)
        if (!((used >> e) & 1u) && p[e] > bp) { bp = p[e]; bi = e; }
      used |= 1u << bi; sp[s] = bp; si[s] = bi;
    }
    float csum = 0.f, wsum = 0.f; bool keep[4];
    #pragma unroll
    for (int s = 0; s < 4; s++) {
      keep[s] = (s < 1) || (csum < 0.9f);
      csum += sp[s];
      if (keep[s]) wsum += sp[s];
    }
    wsum = fmaxf(wsum, 1e-9f);
    if (lane == 0) {
      #pragma unroll
      for (int s = 0; s < 4; s++) {
        sel_e[token * 4 + s] = keep[s] ? si[s] : -1;
        sel_w[token * 4 + s] = keep[s] ? sp[s] / wsum : 0.f;
      }
      #pragma unroll
      for (int e = 0; e < NE; e++) myp[e] += p[e];
      #pragma unroll
      for (int s = 0; s < 4; s++) if (keep[s]) myc[si[s]] += 1.f;
    }
  }
  if (lane == 0) {
    #pragma unroll
    for (int e = 0; e < NE; e++) { atomicAdd(&s_cnt[e], myc[e]); atomicAdd(&s_ps[e], myp[e]); }
  }
  __syncthreads();
  if (tid < NE) {
    part[blockIdx.x * 16 + tid] = s_cnt[tid];
    part[blockIdx.x * 16 + 8 + tid] = s_ps[tid];
  }
}

// ---------------- prep: parallel stat reduction -> aux + expert bases ----------------
// part: [256 blocks][16].  Thread t sums part[t], part[t+256], ... (all ≡ counter t&15).
__global__ __launch_bounds__(256) void prep_kernel(const float* __restrict__ part,
                                                   float* __restrict__ auxp,
                                                   int* __restrict__ meta) {
  __shared__ float red[16];
  int tid = threadIdx.x;
  if (tid < 16) red[tid] = 0.f;
  __syncthreads();
  float s = 0.f;
  #pragma unroll
  for (int m = 0; m < 16; m++) s += part[tid + m * 256];
  atomicAdd(&red[tid & 15], s);
  __syncthreads();
  if (tid == 0) {
    float tot = 0.f;
    for (int e = 0; e < NE; e++) tot += red[e];
    float t = fmaxf(tot, 1.f), acc = 0.f;
    for (int e = 0; e < NE; e++) acc += (red[e] / t) * (red[NE + e] / (float)NTOK);
    auxp[0] = 0.01f * (float)NE * acc;
    int off = 0;
    for (int e = 0; e < NE; e++) {
      int c = (int)(red[e] + 0.5f);
      meta[e] = c; meta[8 + e] = off;
      off += (c + 127) & ~127;   // 128-granule padding (M-tile = 128)
    }
  }
  if (tid < NE) meta[16 + tid] = 0;
}

// ---------------- build compact assignment lists ----------------
__global__ __launch_bounds__(256) void build_kernel(const int* __restrict__ sel_e,
                                                    const float* __restrict__ sel_w,
                                                    int* __restrict__ meta,
                                                    int* __restrict__ mlist,
                                                    float* __restrict__ wrow) {
  __shared__ int lcnt[NE], roff[NE];
  int tid = threadIdx.x;
  if (tid < NE) lcnt[tid] = 0;
  __syncthreads();
  int t = blockIdx.x * 32 + tid;
  int slots[4], es[4];
  bool active = tid < 32;
  if (active) {
    #pragma unroll
    for (int s = 0; s < 4; s++) {
      es[s] = sel_e[t * 4 + s];
      slots[s] = (es[s] >= 0) ? atomicAdd(&lcnt[es[s]], 1) : -1;
    }
  }
  __syncthreads();
  if (tid < NE) roff[tid] = atomicAdd(&meta[16 + tid], lcnt[tid]);
  __syncthreads();
  if (active) {
    #pragma unroll
    for (int s = 0; s < 4; s++) {
      int e = es[s];
      if (e >= 0) {
        int hrow = meta[8 + e] + roff[e] + slots[s];
        mlist[hrow] = t;
        wrow[hrow] = sel_w[t * 4 + s];
      }
    }
  }
}

// ============ barrier-free wave-private pipelined GEMMs ============
// Block = 4 waves (2x2), block tile 128x128, BK=32. Each wave owns a 64x64
// output tile and stages its own 64 A-rows + 64 B-rows into PRIVATE LDS
// (2x duplication vs shared staging; L2 absorbs). NO __syncthreads anywhere:
// pipeline paced by explicit s_waitcnt vmcnt(8) (tile k landed; tile k+1's
// 8 loads stay in flight across the sync point).
// LDS: 4 waves * 2 bufs * (A 4KB + B 4KB) = 64 KB -> 2 blocks/CU.

// ---------------- GEMM1: H[hrow] = bf16(gelu(x[tok] @ W1^T + b1)) ----------------
__global__ __launch_bounds__(256, 2) void gemm1_sp(const short* __restrict__ A,
                                                   const short* __restrict__ W1t,
                                                   const float* __restrict__ b1,
                                                   short* __restrict__ H,
                                                   const int* __restrict__ mlist,
                                                   const int* __restrict__ meta) {
  __shared__ __align__(16) short L[4 * 8192];  // [wave][buf][A 2048 | B 2048]
  int e = blockIdx.x >> 6, j = blockIdx.x & 63;
  int cnt = meta[e];
  if (j * 128 >= cnt) return;
  int base = meta[8 + e];
  int tid = threadIdx.x, wave = tid >> 6, lane = tid & 63;
  int wm = wave >> 1, wn = wave & 1, quad = lane >> 4, l16 = lane & 15;
  int n0 = blockIdx.y * 128;
  const short* Bt = W1t + (size_t)e * DFF * DM;

  // staging addrs: chunk c = g*64+lane -> local row c>>2 (0..63), 16B seg c&3
  const short* ag[4]; const short* bg[4];
  #pragma unroll
  for (int g = 0; g < 4; g++) {
    int c = g * 64 + lane, row = c >> 2, seg = c & 3;
    int rl = j * 128 + wm * 64 + row;
    int tok = mlist[base + (rl < cnt ? rl : cnt - 1)];
    ag[g] = A + (size_t)tok * DM + seg * 8;
    bg[g] = Bt + (size_t)(n0 + wn * 64 + row) * DM + seg * 8;
  }
  short* myL = L + wave * 8192;

  f32x4 acc[4][4];
  #pragma unroll
  for (int i = 0; i < 4; i++)
    #pragma unroll
    for (int jj = 0; jj < 4; jj++) acc[i][jj] = (f32x4){0.f, 0.f, 0.f, 0.f};

  // prologue: stage tile 0 into buf 0 (8 loads)
  #pragma unroll
  for (int g = 0; g < 4; g++) {
    GLD_LDS16(ag[g], myL + g * 512);
    GLD_LDS16(bg[g], myL + 2048 + g * 512);
  }

  for (int kt = 0; kt < DM; kt += 32) {
    int cur = (kt >> 5) & 1;
    const short* cb = myL + cur * 4096;
    if (kt + 32 < DM) {
      short* nb = myL + (cur ^ 1) * 4096;
      #pragma unroll
      for (int g = 0; g < 4; g++) {
        GLD_LDS16(ag[g] + kt + 32, nb + g * 512);
        GLD_LDS16(bg[g] + kt + 32, nb + 2048 + g * 512);
      }
      asm volatile("s_waitcnt vmcnt(8)" ::: "memory");  // tile cur landed; 8 prefetch in flight
    } else {
      asm volatile("s_waitcnt vmcnt(0)" ::: "memory");
    }
    bfrag afr[4], bfr[4];
    #pragma unroll
    for (int mi = 0; mi < 4; mi++)
      afr[mi] = *(const bfrag*)(cb + (mi * 16 + l16) * 32 + quad * 8);
    #pragma unroll
    for (int ni = 0; ni < 4; ni++)
      bfr[ni] = *(const bfrag*)(cb + 2048 + (ni * 16 + l16) * 32 + quad * 8);
    #pragma unroll
    for (int mi = 0; mi < 4; mi++)
      #pragma unroll
      for (int ni = 0; ni < 4; ni++)
        acc[mi][ni] = __builtin_amdgcn_mfma_f32_16x16x32_bf16(afr[mi], bfr[ni], acc[mi][ni], 0, 0, 0);
  }
  const float* bb = b1 + (size_t)e * DFF;
  #pragma unroll
  for (int mi = 0; mi < 4; mi++) {
    int rbase = base + j * 128 + wm * 64 + mi * 16 + quad * 4;
    #pragma unroll
    for (int ni = 0; ni < 4; ni++) {
      int col = n0 + wn * 64 + ni * 16 + l16;
      float bv = bb[col];
      #pragma unroll
      for (int r = 0; r < 4; r++)
        H[(size_t)(rbase + r) * DFF + col] = f2bf(fast_gelu(acc[mi][ni][r] + bv));
    }
  }
}

// ---------------- GEMM2: out[tok] += w * (H[hrow] @ W2^T + b2), fused combine ----------------
__global__ __launch_bounds__(256, 2) void gemm2_sp(const short* __restrict__ H,
                                                   const short* __restrict__ W2t,
                                                   const float* __restrict__ b2,
                                                   float* __restrict__ out,
                                                   const float* __restrict__ wrow,
                                                   const int* __restrict__ mlist,
                                                   const int* __restrict__ meta) {
  __shared__ __align__(16) short L[4 * 8192];
  int e = blockIdx.x >> 6, j = blockIdx.x & 63;
  int cnt = meta[e];
  if (j * 128 >= cnt) return;
  int base = meta[8 + e];
  int tid = threadIdx.x, wave = tid >> 6, lane = tid & 63;
  int wm = wave >> 1, wn = wave & 1, quad = lane >> 4, l16 = lane & 15;
  int n0 = blockIdx.y * 128;
  const short* Bt = W2t + (size_t)e * DM * DFF;

  const short* ag[4]; const short* bg[4];
  #pragma unroll
  for (int g = 0; g < 4; g++) {
    int c = g * 64 + lane, row = c >> 2, seg = c & 3;
    ag[g] = H + (size_t)(base + j * 128 + wm * 64 + row) * DFF + seg * 8;
    bg[g] = Bt + (size_t)(n0 + wn * 64 + row) * DFF + seg * 8;
  }
  short* myL = L + wave * 8192;

  f32x4 acc[4][4];
  #pragma unroll
  for (int i = 0; i < 4; i++)
    #pragma unroll
    for (int jj = 0; jj < 4; jj++) acc[i][jj] = (f32x4){0.f, 0.f, 0.f, 0.f};

  #pragma unroll
  for (int g = 0; g < 4; g++) {
    GLD_LDS16(ag[g], myL + g * 512);
    GLD_LDS16(bg[g], myL + 2048 + g * 512);
  }

  for (int kt = 0; kt < DFF; kt += 32) {
    int cur = (kt >> 5) & 1;
    const short* cb = myL + cur * 4096;
    if (kt + 32 < DFF) {
      short* nb = myL + (cur ^ 1) * 4096;
      #pragma unroll
      for (int g = 0; g < 4; g++) {
        GLD_LDS16(ag[g] + kt + 32, nb + g * 512);
        GLD_LDS16(bg[g] + kt + 32, nb + 2048 + g * 512);
      }
      asm volatile("s_waitcnt vmcnt(8)" ::: "memory");
    } else {
      asm volatile("s_waitcnt vmcnt(0)" ::: "memory");
    }
    bfrag afr[4], bfr[4];
    #pragma unroll
    for (int mi = 0; mi < 4; mi++)
      afr[mi] = *(const bfrag*)(cb + (mi * 16 + l16) * 32 + quad * 8);
    #pragma unroll
    for (int ni = 0; ni < 4; ni++)
      bfr[ni] = *(const bfrag*)(cb + 2048 + (ni * 16 + l16) * 32 + quad * 8);
    #pragma unroll
    for (int mi = 0; mi < 4; mi++)
      #pragma unroll
      for (int ni = 0; ni < 4; ni++)
        acc[mi][ni] = __builtin_amdgcn_mfma_f32_16x16x32_bf16(afr[mi], bfr[ni], acc[mi][ni], 0, 0, 0);
  }
  const float* bb = b2 + (size_t)e * DM;
  #pragma unroll
  for (int mi = 0; mi < 4; mi++) {
    int rl0 = j * 128 + wm * 64 + mi * 16 + quad * 4;
    int toks[4]; float ws[4]; bool ok[4];
    #pragma unroll
    for (int r = 0; r < 4; r++) {
      int rl = rl0 + r;
      ok[r] = rl < cnt;
      int hrow = base + (ok[r] ? rl : 0);
      toks[r] = mlist[hrow];
      ws[r] = wrow[hrow];
    }
    #pragma unroll
    for (int ni = 0; ni < 4; ni++) {
      int col = n0 + wn * 64 + ni * 16 + l16;
      float bv = bb[col];
      #pragma unroll
      for (int r = 0; r < 4; r++)
        if (ok[r]) atomicAdd(&out[(size_t)toks[r] * DM + col], ws[r] * (acc[mi][ni][r] + bv));
    }
  }
}

extern "C" void kernel_launch(void* const* d_in, const int* in_sizes, int n_in,
                              void* d_out, int out_size, void* d_ws, size_t ws_size,
                              hipStream_t stream) {
  const float* x  = (const float*)d_in[0];
  const float* rw = (const float*)d_in[1];
  const float* W1 = (const float*)d_in[2];
  const float* b1 = (const float*)d_in[3];
  const float* W2 = (const float*)d_in[4];
  const float* b2 = (const float*)d_in[5];
  float* out = (float*)d_out;

  char* base_p = (char*)d_ws; char* p = base_p;
  auto carve = [&](size_t bytes) { char* r = p; p += (bytes + 255) & ~(size_t)255; return r; };
  short* xb    = (short*)carve((size_t)NTOK * DM * 2);
  short* w1b   = (short*)carve((size_t)NE * DM * DFF * 2);  // [e][DFF][DM]
  short* w2b   = (short*)carve((size_t)NE * DFF * DM * 2);  // [e][DM][DFF]
  int*   sel_e = (int*)carve((size_t)NTOK * 4 * 4);
  float* sel_w = (float*)carve((size_t)NTOK * 4 * 4);
  float* part  = (float*)carve(256 * 16 * 4);
  int*   meta  = (int*)carve(64 * 4);
  int*   mlist = (int*)carve((size_t)ROWCAP * 4);
  float* wrow  = (float*)carve((size_t)ROWCAP * 4);
  short* Hbig  = (short*)carve((size_t)ROWCAP * DFF * 2);

  hipMemsetAsync(out, 0, (size_t)NTOK * DM * 4, stream);
  cvt_kernel<<<(NTOK * DM / 4 + 255) / 256, 256, 0, stream>>>(x, xb, NTOK * DM / 4);
  cvtT_kernel<<<dim3(DM / 32, DFF / 32, NE), 256, 0, stream>>>(W1, w1b, DM, DFF);
  cvtT_kernel<<<dim3(DFF / 32, DM / 32, NE), 256, 0, stream>>>(W2, w2b, DFF, DM);
  router_kernel<<<256, 256, 0, stream>>>(x, rw, sel_e, sel_w, part);
  prep_kernel<<<1, 256, 0, stream>>>(part, out + (size_t)NTOK * DM, meta);
  build_kernel<<<256, 256, 0, stream>>>(sel_e, sel_w, meta, mlist, wrow);
  gemm1_sp<<<dim3(NE * 64, DFF / 128), 256, 0, stream>>>(xb, w1b, b1, Hbig, mlist, meta);
  gemm2_sp<<<dim3(NE * 64, DM / 128), 256, 0, stream>>>(Hbig, w2b, b2, out, wrow, mlist, meta);
}